// Round 3
// baseline (423.217 us; speedup 1.0000x reference)
//
#include <hip/hip_runtime.h>
#include <cfloat>
#include <math.h>

#define B_ 8
#define C_ 256
#define C2_ (C_/2)            // uints (bf16 pairs) per pixel row
#define H_ 128
#define W_ 128
#define N_ (H_*W_)            // 16384
#define NRAND 32
#define NHARD 96
#define NPOS 256
#define INV_TEMP (1.0f/0.07f)

typedef float f32x4 __attribute__((ext_vector_type(4)));
typedef short bf16x8 __attribute__((ext_vector_type(8)));
union Frag { uint4 u; bf16x8 s; };

__device__ __forceinline__ unsigned bf16rne(float x) {
    unsigned u = __float_as_uint(x);
    return (u + 0x7FFFu + ((u >> 16) & 1u)) >> 16;
}
__device__ __forceinline__ float blo(unsigned w) { return __uint_as_float(w << 16); }
__device__ __forceinline__ float bhi(unsigned w) { return __uint_as_float(w & 0xFFFF0000u); }

// ---------------------------------------------------------------------------
// k1: transpose both fmaps to raw-bf16 [b][n][c] + write fp32 inv-norms.
// Block = 256-px tile, 4 chunks of 64 ch. float4 loads (1KB/wave-instr),
// bf16 packed LDS staging (stride 260 uints, 16B-aligned b128 writes),
// coalesced uint2 stores (128B/16 lanes).
// ---------------------------------------------------------------------------
__global__ __launch_bounds__(256) void k1_norm_T(
        const float* __restrict__ rgb, const float* __restrict__ dep,
        unsigned* __restrict__ rgbT, unsigned* __restrict__ depT,
        float* __restrict__ invn) {
    __shared__ unsigned tile_u[32 * 260];
    __shared__ float red[4 * 256];
    int bi  = blockIdx.x;
    int map = bi >> 9;
    int b   = (bi >> 6) & 7;
    int p0  = (bi & 63) << 8;
    int t   = threadIdx.x;
    int w   = t >> 6, l = t & 63;
    const float* src = (map ? dep : rgb) + (size_t)b * C_ * N_;
    unsigned*    dst = (map ? depT : rgbT) + (size_t)b * N_ * C2_;
    float4 ssq = make_float4(0.f, 0.f, 0.f, 0.f);
    for (int chunk = 0; chunk < 4; ++chunk) {
        #pragma unroll
        for (int i = 0; i < 8; ++i) {
            int pp  = w * 8 + i;
            int chA = chunk * 64 + 2 * pp;
            const float4* sa = (const float4*)(src + (size_t)chA * N_ + p0);
            const float4* sb = (const float4*)(src + (size_t)(chA + 1) * N_ + p0);
            float4 va = sa[l], vb = sb[l];
            ssq.x += va.x * va.x + vb.x * vb.x;
            ssq.y += va.y * va.y + vb.y * vb.y;
            ssq.z += va.z * va.z + vb.z * vb.z;
            ssq.w += va.w * va.w + vb.w * vb.w;
            uint4 o;
            o.x = bf16rne(va.x) | (bf16rne(vb.x) << 16);
            o.y = bf16rne(va.y) | (bf16rne(vb.y) << 16);
            o.z = bf16rne(va.z) | (bf16rne(vb.z) << 16);
            o.w = bf16rne(va.w) | (bf16rne(vb.w) << 16);
            *(uint4*)&tile_u[pp * 260 + 4 * l] = o;
        }
        __syncthreads();
        #pragma unroll
        for (int it = 0; it < 16; ++it) {
            int px = it * 16 + (t >> 4);
            int a  = t & 15;
            unsigned u0 = tile_u[(2 * a) * 260 + px];
            unsigned u1 = tile_u[(2 * a + 1) * 260 + px];
            *(uint2*)(dst + (size_t)(p0 + px) * C2_ + chunk * 32 + 2 * a) =
                make_uint2(u0, u1);
        }
        __syncthreads();
    }
    red[w * 256 + 4 * l + 0] = ssq.x;
    red[w * 256 + 4 * l + 1] = ssq.y;
    red[w * 256 + 4 * l + 2] = ssq.z;
    red[w * 256 + 4 * l + 3] = ssq.w;
    __syncthreads();
    float s = red[t] + red[256 + t] + red[512 + t] + red[768 + t];
    invn[(size_t)map * B_ * N_ + b * N_ + p0 + t] =
        1.0f / fmaxf(sqrtf(s), 1e-12f);
}

// ---------------------------------------------------------------------------
// k2: per 64-px block. Phase 1: rand einsum via MFMA 16x16x32 bf16
// (wave = 16 px x 32 rand, K=256; A/B fragments loaded straight from
// depT/rgbT rows — k-contiguous). Phase 2: bilinear pos on VALU from bf16
// rows; combine with rand lse via tiny LDS handoff.
// ---------------------------------------------------------------------------
__global__ __launch_bounds__(256) void k2_main(
        const unsigned* __restrict__ depT, const unsigned* __restrict__ rgbT,
        const float* __restrict__ invn, const float* __restrict__ coords,
        const int* __restrict__ rand_idx, float* __restrict__ lse_base,
        float* __restrict__ pos_out, float* __restrict__ maxneg_out) {
    __shared__ float mneg_s[64], se_s[64];
    int bi = blockIdx.x;
    int b  = bi >> 8;
    int p0 = (bi & 255) << 6;
    int t  = threadIdx.x;
    int w  = t >> 6, l = t & 63;
    const float* invnR = invn;
    const float* invnD = invn + B_ * N_;
    // ---- Phase 1: MFMA rand einsum ----
    int m_base = p0 + w * 16;
    int rowA   = m_base + (l & 15);
    int quad   = l >> 4;
    const uint4* aptr = (const uint4*)(depT + (size_t)(b * N_ + rowA) * C2_) + quad;
    int q0 = rand_idx[b * NRAND + (l & 15)];
    int q1 = rand_idx[b * NRAND + 16 + (l & 15)];
    const uint4* bptr0 = (const uint4*)(rgbT + (size_t)(b * N_ + q0) * C2_) + quad;
    const uint4* bptr1 = (const uint4*)(rgbT + (size_t)(b * N_ + q1) * C2_) + quad;
    f32x4 acc0 = {0.f, 0.f, 0.f, 0.f}, acc1 = {0.f, 0.f, 0.f, 0.f};
    #pragma unroll 4
    for (int ks = 0; ks < 8; ++ks) {
        Frag a, b0, b1;
        a.u  = aptr[ks * 4];
        b0.u = bptr0[ks * 4];
        b1.u = bptr1[ks * 4];
        acc0 = __builtin_amdgcn_mfma_f32_16x16x32_bf16(a.s, b0.s, acc0, 0, 0, 0);
        acc1 = __builtin_amdgcn_mfma_f32_16x16x32_bf16(a.s, b1.s, acc1, 0, 0, 0);
    }
    float rn0 = invnR[b * N_ + q0], rn1 = invnR[b * N_ + q1];
    int rbase = m_base + quad * 4;
    #pragma unroll
    for (int r = 0; r < 4; ++r) {
        float dm = invnD[b * N_ + rbase + r] * INV_TEMP;
        float x0 = acc0[r] * rn0 * dm;
        float x1 = acc1[r] * rn1 * dm;
        float mx = fmaxf(x0, x1);
        mx = fmaxf(mx, __shfl_xor(mx, 1, 16));
        mx = fmaxf(mx, __shfl_xor(mx, 2, 16));
        mx = fmaxf(mx, __shfl_xor(mx, 4, 16));
        mx = fmaxf(mx, __shfl_xor(mx, 8, 16));
        float e = expf(x0 - mx) + expf(x1 - mx);
        e += __shfl_xor(e, 1, 16);
        e += __shfl_xor(e, 2, 16);
        e += __shfl_xor(e, 4, 16);
        e += __shfl_xor(e, 8, 16);
        if ((l & 15) == 0) {
            mneg_s[w * 16 + quad * 4 + r] = mx;
            se_s[w * 16 + quad * 4 + r]   = e;
        }
    }
    __syncthreads();
    // ---- Phase 2: bilinear pos ----
    int px = t >> 2, g = t & 3;
    int n  = p0 + px;
    float xf = coords[(size_t)b * 2 * N_ + n];
    float yf = coords[(size_t)b * 2 * N_ + N_ + n];
    float x0f = floorf(xf), y0f = floorf(yf);
    float wx = xf - x0f, wy = yf - y0f;
    int ix = (int)x0f + (g & 1);
    int iy = (int)y0f + (g >> 1);
    float wgt = ((g & 1) ? wx : 1.f - wx) * ((g & 2) ? wy : 1.f - wy);
    if (ix < 0 || ix >= W_ || iy < 0 || iy >= H_) wgt = 0.f;
    int ixc = min(max(ix, 0), W_ - 1), iyc = min(max(iy, 0), H_ - 1);
    int nq  = iyc * W_ + ixc;
    const uint4* dp = (const uint4*)(depT + (size_t)(b * N_ + n) * C2_);
    const uint4* nb = (const uint4*)(rgbT + (size_t)(b * N_ + nq) * C2_);
    float acc = 0.f;
    #pragma unroll 8
    for (int i = 0; i < 32; ++i) {
        uint4 d = dp[i], q = nb[i];
        acc += blo(d.x) * blo(q.x) + bhi(d.x) * bhi(q.x)
             + blo(d.y) * blo(q.y) + bhi(d.y) * bhi(q.y)
             + blo(d.z) * blo(q.z) + bhi(d.z) * bhi(q.z)
             + blo(d.w) * blo(q.w) + bhi(d.w) * bhi(q.w);
    }
    float pp = acc * wgt * invnR[b * N_ + nq];
    pp += __shfl_xor(pp, 1, 4);
    pp += __shfl_xor(pp, 2, 4);
    float pos = pp * invnD[b * N_ + n] * INV_TEMP;
    if (g == 0) {
        float mn = mneg_s[px], se = se_s[px];
        float mall = fmaxf(mn, pos);
        float lse = mall + logf(se * expf(mn - mall) + expf(pos - mall));
        size_t o = (size_t)b * N_ + n;
        lse_base[o]   = lse;
        pos_out[o]    = pos;
        maxneg_out[o] = mn;
    }
}

// ---------------------------------------------------------------------------
// k3: hard negatives from bf16 rows. One block per (b, grid-point).
// ---------------------------------------------------------------------------
__global__ __launch_bounds__(128) void k3_hard(
        const unsigned* __restrict__ depT, const unsigned* __restrict__ rgbT,
        const float* __restrict__ invn, const float* __restrict__ coords,
        const int* __restrict__ hoffu, const int* __restrict__ hoffv,
        float* __restrict__ lse_hard, float* __restrict__ max_hard) {
    __shared__ __align__(16) float dv[256];
    __shared__ float sm_[2], ss_[2];
    int bp = blockIdx.x;
    int b = bp >> 8, p = bp & 255;
    int gy = (p >> 4) * 8, gx = (p & 15) * 8;
    int n  = gy * W_ + gx;
    int t  = threadIdx.x;
    const float* invnR = invn;
    const float* invnD = invn + B_ * N_;
    unsigned wv = depT[(size_t)(b * N_ + n) * C2_ + t];
    dv[2 * t]     = blo(wv);
    dv[2 * t + 1] = bhi(wv);
    float inv_d = invnD[b * N_ + n];
    float pu = coords[(size_t)b * 2 * N_ + n];
    float pv = coords[(size_t)b * 2 * N_ + N_ + n];
    int iu = (int)fminf(fmaxf(pu, 0.f), (float)(W_ - 1));
    int iv = (int)fminf(fmaxf(pv, 0.f), (float)(H_ - 1));
    __syncthreads();
    float sim = -FLT_MAX;
    if (t < NHARD) {
        int ou = hoffu[((size_t)b * NHARD + t) * NPOS + p];
        int ov = hoffv[((size_t)b * NHARD + t) * NPOS + p];
        if (ou == 0 && ov == 0) ou = 1;
        int hu = min(max(iu + ou, 0), W_ - 1);
        int hv = min(max(iv + ov, 0), H_ - 1);
        int hq = hv * W_ + hu;
        const uint4* hvec = (const uint4*)(rgbT + (size_t)(b * N_ + hq) * C2_);
        float acc = 0.f;
        #pragma unroll 8
        for (int i = 0; i < 32; ++i) {
            uint4 q = hvec[i];
            float4 d0 = *(const float4*)&dv[i * 8];
            float4 d1 = *(const float4*)&dv[i * 8 + 4];
            acc += d0.x * blo(q.x) + d0.y * bhi(q.x)
                 + d0.z * blo(q.y) + d0.w * bhi(q.y)
                 + d1.x * blo(q.z) + d1.y * bhi(q.z)
                 + d1.z * blo(q.w) + d1.w * bhi(q.w);
        }
        sim = acc * inv_d * invnR[b * N_ + hq] * INV_TEMP;
    }
    int wid = t >> 6;
    float m = sim;
    #pragma unroll
    for (int o = 32; o > 0; o >>= 1) m = fmaxf(m, __shfl_down(m, o, 64));
    if ((t & 63) == 0) sm_[wid] = m;
    __syncthreads();
    float mm = fmaxf(sm_[0], sm_[1]);
    float e = (t < NHARD) ? expf(sim - mm) : 0.f;
    #pragma unroll
    for (int o = 32; o > 0; o >>= 1) e += __shfl_down(e, o, 64);
    if ((t & 63) == 0) ss_[wid] = e;
    __syncthreads();
    if (t == 0) {
        lse_hard[bp] = mm + logf(ss_[0] + ss_[1]);
        max_hard[bp] = mm;
    }
}

// ---------------------------------------------------------------------------
// k4: masked reduction over all pixels (with grid-point hard fix-up).
// ---------------------------------------------------------------------------
__global__ __launch_bounds__(256) void k4_reduce(
        const float* __restrict__ lse_base, const float* __restrict__ pos_sim,
        const float* __restrict__ max_neg, const float* __restrict__ mask,
        const float* __restrict__ lse_hard, const float* __restrict__ max_hard,
        float* __restrict__ acc) {
    int i = blockIdx.x * 256 + threadIdx.x;
    float l  = lse_base[i], ps = pos_sim[i], mn = max_neg[i], mk = mask[i];
    int b = i >> 14;
    int n = i & (N_ - 1);
    int y = n >> 7, x = n & 127;
    if (((y & 7) | (x & 7)) == 0) {
        int p = ((y >> 3) << 4) + (x >> 3);
        float lh = lse_hard[(b << 8) + p];
        float mh = max_hard[(b << 8) + p];
        float m = fmaxf(l, lh);
        l  = m + logf(expf(l - m) + expf(lh - m));
        mn = fmaxf(mn, mh);
    }
    float s0 = (l - ps) * mk;
    float s1 = (ps > mn && mk > 0.5f) ? 1.f : 0.f;
    float s2 = mk;
    #pragma unroll
    for (int o = 32; o > 0; o >>= 1) {
        s0 += __shfl_down(s0, o, 64);
        s1 += __shfl_down(s1, o, 64);
        s2 += __shfl_down(s2, o, 64);
    }
    __shared__ float r0[4], r1[4], r2[4];
    int wid = threadIdx.x >> 6;
    if ((threadIdx.x & 63) == 0) { r0[wid] = s0; r1[wid] = s1; r2[wid] = s2; }
    __syncthreads();
    if (threadIdx.x == 0) {
        atomicAdd(&acc[0], r0[0] + r0[1] + r0[2] + r0[3]);
        atomicAdd(&acc[1], r1[0] + r1[1] + r1[2] + r1[3]);
        atomicAdd(&acc[2], r2[0] + r2[1] + r2[2] + r2[3]);
    }
}

__global__ void k5_final(const float* __restrict__ acc, float* __restrict__ out) {
    if (threadIdx.x == 0) {
        float denom = fmaxf(acc[2], 1.0f);
        out[0] = acc[0] / denom;
        out[1] = acc[1] / denom * 100.0f;
    }
}

extern "C" void kernel_launch(void* const* d_in, const int* in_sizes, int n_in,
                              void* d_out, int out_size, void* d_ws, size_t ws_size,
                              hipStream_t stream) {
    const float* rgb     = (const float*)d_in[0];
    const float* dep     = (const float*)d_in[1];
    const float* coords  = (const float*)d_in[2];
    const float* mask    = (const float*)d_in[3];
    const int*   rand_i  = (const int*)d_in[4];
    const int*   hoffu   = (const int*)d_in[5];
    const int*   hoffv   = (const int*)d_in[6];
    float* out = (float*)d_out;
    char*  ws  = (char*)d_ws;

    const size_t MAP_B = (size_t)B_ * N_ * C_ * 2;       // 67108864 per map
    const size_t PIX_B = (size_t)B_ * N_ * 4;            // 524288
    unsigned* rgbT  = (unsigned*)ws;
    unsigned* depT  = (unsigned*)(ws + MAP_B);
    float* invn     = (float*)(ws + 2 * MAP_B);          // [2][B][N]
    float* lse_base = (float*)(ws + 2 * MAP_B + 2 * PIX_B);
    float* pos_sim  = (float*)(ws + 2 * MAP_B + 3 * PIX_B);
    float* max_neg  = (float*)(ws + 2 * MAP_B + 4 * PIX_B);
    float* lse_hard = (float*)(ws + 2 * MAP_B + 5 * PIX_B);
    float* max_hard = (float*)(ws + 2 * MAP_B + 5 * PIX_B + 8192);
    float* acc      = (float*)(ws + 2 * MAP_B + 5 * PIX_B + 2 * 8192);

    hipMemsetAsync(acc, 0, 16, stream);
    k1_norm_T<<<1024, 256, 0, stream>>>(rgb, dep, rgbT, depT, invn);
    k2_main<<<B_ * (N_ / 64), 256, 0, stream>>>(depT, rgbT, invn, coords, rand_i,
                                                lse_base, pos_sim, max_neg);
    k3_hard<<<B_ * NPOS, 128, 0, stream>>>(depT, rgbT, invn, coords, hoffu, hoffv,
                                           lse_hard, max_hard);
    k4_reduce<<<(B_ * N_) / 256, 256, 0, stream>>>(lse_base, pos_sim, max_neg,
                                                   mask, lse_hard, max_hard, acc);
    k5_final<<<1, 64, 0, stream>>>(acc, out);
}

// Round 4
// 419.990 us; speedup vs baseline: 1.0077x; 1.0077x over previous
//
#include <hip/hip_runtime.h>
#include <cfloat>
#include <math.h>

#define B_ 8
#define C_ 256
#define C2_ (C_/2)            // uints (bf16 pairs) per pixel row
#define H_ 128
#define W_ 128
#define N_ (H_*W_)            // 16384
#define NRAND 32
#define NHARD 96
#define NPOS 256
#define INV_TEMP (1.0f/0.07f)

typedef float f32x4 __attribute__((ext_vector_type(4)));
typedef short bf16x8 __attribute__((ext_vector_type(8)));
union Frag { uint4 u; bf16x8 s; };

__device__ __forceinline__ unsigned bf16rne(float x) {
    unsigned u = __float_as_uint(x);
    return (u + 0x7FFFu + ((u >> 16) & 1u)) >> 16;
}
__device__ __forceinline__ float blo(unsigned w) { return __uint_as_float(w << 16); }
__device__ __forceinline__ float bhi(unsigned w) { return __uint_as_float(w & 0xFFFF0000u); }

// ---------------------------------------------------------------------------
// k1 v2: transpose both fmaps to raw-bf16 [b][n][c] + fp32 inv-norms.
// 128-px tile (grid 2048 -> ~8 blocks/CU resident), 4 chunks of 64 ch.
// Reads: float4, 1KB/wave-instr (2 rows x 512B). Stores: uint4, 1KB/wave-instr
// (8 px-rows x 128B contiguous). LDS tile pair-major stride 132 (aligned b128
// writes; 4-way b32 read conflicts on store path are negligible).
// ---------------------------------------------------------------------------
__global__ __launch_bounds__(256) void k1_norm_T(
        const float* __restrict__ rgb, const float* __restrict__ dep,
        unsigned* __restrict__ rgbT, unsigned* __restrict__ depT,
        float* __restrict__ invn) {
    __shared__ unsigned tileU[32 * 132];
    __shared__ float red[8 * 132];
    int bi  = blockIdx.x;
    int map = bi >> 10;
    int b   = (bi >> 7) & 7;
    int p0  = (bi & 127) << 7;
    int t   = threadIdx.x;
    int f4  = t & 31;                 // px-quad 0..31 (covers 128 px)
    int r   = t >> 5;                 // 0..7
    const float* src = (map ? dep : rgb) + (size_t)b * C_ * N_;
    unsigned*    dst = (map ? depT : rgbT) + (size_t)b * N_ * C2_;
    float4 ssq = make_float4(0.f, 0.f, 0.f, 0.f);
    int a = t & 7, pxg = t >> 3;      // store-path mapping
    for (int chunk = 0; chunk < 4; ++chunk) {
        #pragma unroll
        for (int i = 0; i < 4; ++i) {
            int pair = i * 8 + r;
            int chA  = chunk * 64 + 2 * pair;
            float4 va = ((const float4*)(src + (size_t)chA * N_ + p0))[f4];
            float4 vb = ((const float4*)(src + (size_t)(chA + 1) * N_ + p0))[f4];
            ssq.x += va.x * va.x + vb.x * vb.x;
            ssq.y += va.y * va.y + vb.y * vb.y;
            ssq.z += va.z * va.z + vb.z * vb.z;
            ssq.w += va.w * va.w + vb.w * vb.w;
            uint4 o;
            o.x = bf16rne(va.x) | (bf16rne(vb.x) << 16);
            o.y = bf16rne(va.y) | (bf16rne(vb.y) << 16);
            o.z = bf16rne(va.z) | (bf16rne(vb.z) << 16);
            o.w = bf16rne(va.w) | (bf16rne(vb.w) << 16);
            *(uint4*)&tileU[pair * 132 + 4 * f4] = o;
        }
        __syncthreads();
        #pragma unroll
        for (int it = 0; it < 4; ++it) {
            int px = it * 32 + pxg;
            uint4 o;
            o.x = tileU[(4 * a + 0) * 132 + px];
            o.y = tileU[(4 * a + 1) * 132 + px];
            o.z = tileU[(4 * a + 2) * 132 + px];
            o.w = tileU[(4 * a + 3) * 132 + px];
            *(uint4*)(dst + (size_t)(p0 + px) * C2_ + chunk * 32 + 4 * a) = o;
        }
        __syncthreads();
    }
    red[r * 132 + 4 * f4 + 0] = ssq.x;
    red[r * 132 + 4 * f4 + 1] = ssq.y;
    red[r * 132 + 4 * f4 + 2] = ssq.z;
    red[r * 132 + 4 * f4 + 3] = ssq.w;
    __syncthreads();
    if (t < 128) {
        float s = 0.f;
        #pragma unroll
        for (int rr = 0; rr < 8; ++rr) s += red[rr * 132 + t];
        invn[(size_t)map * B_ * N_ + b * N_ + p0 + t] =
            1.0f / fmaxf(sqrtf(s), 1e-12f);
    }
}

// ---------------------------------------------------------------------------
// k2: per 64-px block. Phase 1: rand einsum via MFMA 16x16x32 bf16
// (wave = 16 px x 32 rand, K=256; fragments straight from depT/rgbT rows).
// Phase 2: bilinear pos on VALU from bf16 rows; tiny LDS handoff.
// ---------------------------------------------------------------------------
__global__ __launch_bounds__(256) void k2_main(
        const unsigned* __restrict__ depT, const unsigned* __restrict__ rgbT,
        const float* __restrict__ invn, const float* __restrict__ coords,
        const int* __restrict__ rand_idx, float* __restrict__ lse_base,
        float* __restrict__ pos_out, float* __restrict__ maxneg_out) {
    __shared__ float mneg_s[64], se_s[64];
    int bi = blockIdx.x;
    int b  = bi >> 8;
    int p0 = (bi & 255) << 6;
    int t  = threadIdx.x;
    int w  = t >> 6, l = t & 63;
    const float* invnR = invn;
    const float* invnD = invn + B_ * N_;
    // ---- Phase 1: MFMA rand einsum ----
    int m_base = p0 + w * 16;
    int rowA   = m_base + (l & 15);
    int quad   = l >> 4;
    const uint4* aptr = (const uint4*)(depT + (size_t)(b * N_ + rowA) * C2_) + quad;
    int q0 = rand_idx[b * NRAND + (l & 15)];
    int q1 = rand_idx[b * NRAND + 16 + (l & 15)];
    const uint4* bptr0 = (const uint4*)(rgbT + (size_t)(b * N_ + q0) * C2_) + quad;
    const uint4* bptr1 = (const uint4*)(rgbT + (size_t)(b * N_ + q1) * C2_) + quad;
    f32x4 acc0 = {0.f, 0.f, 0.f, 0.f}, acc1 = {0.f, 0.f, 0.f, 0.f};
    #pragma unroll 4
    for (int ks = 0; ks < 8; ++ks) {
        Frag a, b0, b1;
        a.u  = aptr[ks * 4];
        b0.u = bptr0[ks * 4];
        b1.u = bptr1[ks * 4];
        acc0 = __builtin_amdgcn_mfma_f32_16x16x32_bf16(a.s, b0.s, acc0, 0, 0, 0);
        acc1 = __builtin_amdgcn_mfma_f32_16x16x32_bf16(a.s, b1.s, acc1, 0, 0, 0);
    }
    float rn0 = invnR[b * N_ + q0], rn1 = invnR[b * N_ + q1];
    int rbase = m_base + quad * 4;
    #pragma unroll
    for (int r = 0; r < 4; ++r) {
        float dm = invnD[b * N_ + rbase + r] * INV_TEMP;
        float x0 = acc0[r] * rn0 * dm;
        float x1 = acc1[r] * rn1 * dm;
        float mx = fmaxf(x0, x1);
        mx = fmaxf(mx, __shfl_xor(mx, 1, 16));
        mx = fmaxf(mx, __shfl_xor(mx, 2, 16));
        mx = fmaxf(mx, __shfl_xor(mx, 4, 16));
        mx = fmaxf(mx, __shfl_xor(mx, 8, 16));
        float e = expf(x0 - mx) + expf(x1 - mx);
        e += __shfl_xor(e, 1, 16);
        e += __shfl_xor(e, 2, 16);
        e += __shfl_xor(e, 4, 16);
        e += __shfl_xor(e, 8, 16);
        if ((l & 15) == 0) {
            mneg_s[w * 16 + quad * 4 + r] = mx;
            se_s[w * 16 + quad * 4 + r]   = e;
        }
    }
    __syncthreads();
    // ---- Phase 2: bilinear pos ----
    int px = t >> 2, g = t & 3;
    int n  = p0 + px;
    float xf = coords[(size_t)b * 2 * N_ + n];
    float yf = coords[(size_t)b * 2 * N_ + N_ + n];
    float x0f = floorf(xf), y0f = floorf(yf);
    float wx = xf - x0f, wy = yf - y0f;
    int ix = (int)x0f + (g & 1);
    int iy = (int)y0f + (g >> 1);
    float wgt = ((g & 1) ? wx : 1.f - wx) * ((g & 2) ? wy : 1.f - wy);
    if (ix < 0 || ix >= W_ || iy < 0 || iy >= H_) wgt = 0.f;
    int ixc = min(max(ix, 0), W_ - 1), iyc = min(max(iy, 0), H_ - 1);
    int nq  = iyc * W_ + ixc;
    const uint4* dp = (const uint4*)(depT + (size_t)(b * N_ + n) * C2_);
    const uint4* nb = (const uint4*)(rgbT + (size_t)(b * N_ + nq) * C2_);
    float acc = 0.f;
    #pragma unroll 8
    for (int i = 0; i < 32; ++i) {
        uint4 d = dp[i], q = nb[i];
        acc += blo(d.x) * blo(q.x) + bhi(d.x) * bhi(q.x)
             + blo(d.y) * blo(q.y) + bhi(d.y) * bhi(q.y)
             + blo(d.z) * blo(q.z) + bhi(d.z) * bhi(q.z)
             + blo(d.w) * blo(q.w) + bhi(d.w) * bhi(q.w);
    }
    float pp = acc * wgt * invnR[b * N_ + nq];
    pp += __shfl_xor(pp, 1, 4);
    pp += __shfl_xor(pp, 2, 4);
    float pos = pp * invnD[b * N_ + n] * INV_TEMP;
    if (g == 0) {
        float mn = mneg_s[px], se = se_s[px];
        float mall = fmaxf(mn, pos);
        float lse = mall + logf(se * expf(mn - mall) + expf(pos - mall));
        size_t o = (size_t)b * N_ + n;
        lse_base[o]   = lse;
        pos_out[o]    = pos;
        maxneg_out[o] = mn;
    }
}

// ---------------------------------------------------------------------------
// k3: hard negatives from bf16 rows. One block per (b, grid-point).
// ---------------------------------------------------------------------------
__global__ __launch_bounds__(128) void k3_hard(
        const unsigned* __restrict__ depT, const unsigned* __restrict__ rgbT,
        const float* __restrict__ invn, const float* __restrict__ coords,
        const int* __restrict__ hoffu, const int* __restrict__ hoffv,
        float* __restrict__ lse_hard, float* __restrict__ max_hard) {
    __shared__ __align__(16) float dv[256];
    __shared__ float sm_[2], ss_[2];
    int bp = blockIdx.x;
    int b = bp >> 8, p = bp & 255;
    int gy = (p >> 4) * 8, gx = (p & 15) * 8;
    int n  = gy * W_ + gx;
    int t  = threadIdx.x;
    const float* invnR = invn;
    const float* invnD = invn + B_ * N_;
    unsigned wv = depT[(size_t)(b * N_ + n) * C2_ + t];
    dv[2 * t]     = blo(wv);
    dv[2 * t + 1] = bhi(wv);
    float inv_d = invnD[b * N_ + n];
    float pu = coords[(size_t)b * 2 * N_ + n];
    float pv = coords[(size_t)b * 2 * N_ + N_ + n];
    int iu = (int)fminf(fmaxf(pu, 0.f), (float)(W_ - 1));
    int iv = (int)fminf(fmaxf(pv, 0.f), (float)(H_ - 1));
    __syncthreads();
    float sim = -FLT_MAX;
    if (t < NHARD) {
        int ou = hoffu[((size_t)b * NHARD + t) * NPOS + p];
        int ov = hoffv[((size_t)b * NHARD + t) * NPOS + p];
        if (ou == 0 && ov == 0) ou = 1;
        int hu = min(max(iu + ou, 0), W_ - 1);
        int hv = min(max(iv + ov, 0), H_ - 1);
        int hq = hv * W_ + hu;
        const uint4* hvec = (const uint4*)(rgbT + (size_t)(b * N_ + hq) * C2_);
        float acc = 0.f;
        #pragma unroll 8
        for (int i = 0; i < 32; ++i) {
            uint4 q = hvec[i];
            float4 d0 = *(const float4*)&dv[i * 8];
            float4 d1 = *(const float4*)&dv[i * 8 + 4];
            acc += d0.x * blo(q.x) + d0.y * bhi(q.x)
                 + d0.z * blo(q.y) + d0.w * bhi(q.y)
                 + d1.x * blo(q.z) + d1.y * bhi(q.z)
                 + d1.z * blo(q.w) + d1.w * bhi(q.w);
        }
        sim = acc * inv_d * invnR[b * N_ + hq] * INV_TEMP;
    }
    int wid = t >> 6;
    float m = sim;
    #pragma unroll
    for (int o = 32; o > 0; o >>= 1) m = fmaxf(m, __shfl_down(m, o, 64));
    if ((t & 63) == 0) sm_[wid] = m;
    __syncthreads();
    float mm = fmaxf(sm_[0], sm_[1]);
    float e = (t < NHARD) ? expf(sim - mm) : 0.f;
    #pragma unroll
    for (int o = 32; o > 0; o >>= 1) e += __shfl_down(e, o, 64);
    if ((t & 63) == 0) ss_[wid] = e;
    __syncthreads();
    if (t == 0) {
        lse_hard[bp] = mm + logf(ss_[0] + ss_[1]);
        max_hard[bp] = mm;
    }
}

// ---------------------------------------------------------------------------
// k4: masked reduction over all pixels (with grid-point hard fix-up).
// ---------------------------------------------------------------------------
__global__ __launch_bounds__(256) void k4_reduce(
        const float* __restrict__ lse_base, const float* __restrict__ pos_sim,
        const float* __restrict__ max_neg, const float* __restrict__ mask,
        const float* __restrict__ lse_hard, const float* __restrict__ max_hard,
        float* __restrict__ acc) {
    int i = blockIdx.x * 256 + threadIdx.x;
    float l  = lse_base[i], ps = pos_sim[i], mn = max_neg[i], mk = mask[i];
    int b = i >> 14;
    int n = i & (N_ - 1);
    int y = n >> 7, x = n & 127;
    if (((y & 7) | (x & 7)) == 0) {
        int p = ((y >> 3) << 4) + (x >> 3);
        float lh = lse_hard[(b << 8) + p];
        float mh = max_hard[(b << 8) + p];
        float m = fmaxf(l, lh);
        l  = m + logf(expf(l - m) + expf(lh - m));
        mn = fmaxf(mn, mh);
    }
    float s0 = (l - ps) * mk;
    float s1 = (ps > mn && mk > 0.5f) ? 1.f : 0.f;
    float s2 = mk;
    #pragma unroll
    for (int o = 32; o > 0; o >>= 1) {
        s0 += __shfl_down(s0, o, 64);
        s1 += __shfl_down(s1, o, 64);
        s2 += __shfl_down(s2, o, 64);
    }
    __shared__ float r0[4], r1[4], r2[4];
    int wid = threadIdx.x >> 6;
    if ((threadIdx.x & 63) == 0) { r0[wid] = s0; r1[wid] = s1; r2[wid] = s2; }
    __syncthreads();
    if (threadIdx.x == 0) {
        atomicAdd(&acc[0], r0[0] + r0[1] + r0[2] + r0[3]);
        atomicAdd(&acc[1], r1[0] + r1[1] + r1[2] + r1[3]);
        atomicAdd(&acc[2], r2[0] + r2[1] + r2[2] + r2[3]);
    }
}

__global__ void k5_final(const float* __restrict__ acc, float* __restrict__ out) {
    if (threadIdx.x == 0) {
        float denom = fmaxf(acc[2], 1.0f);
        out[0] = acc[0] / denom;
        out[1] = acc[1] / denom * 100.0f;
    }
}

extern "C" void kernel_launch(void* const* d_in, const int* in_sizes, int n_in,
                              void* d_out, int out_size, void* d_ws, size_t ws_size,
                              hipStream_t stream) {
    const float* rgb     = (const float*)d_in[0];
    const float* dep     = (const float*)d_in[1];
    const float* coords  = (const float*)d_in[2];
    const float* mask    = (const float*)d_in[3];
    const int*   rand_i  = (const int*)d_in[4];
    const int*   hoffu   = (const int*)d_in[5];
    const int*   hoffv   = (const int*)d_in[6];
    float* out = (float*)d_out;
    char*  ws  = (char*)d_ws;

    const size_t MAP_B = (size_t)B_ * N_ * C_ * 2;       // 67108864 per map
    const size_t PIX_B = (size_t)B_ * N_ * 4;            // 524288
    unsigned* rgbT  = (unsigned*)ws;
    unsigned* depT  = (unsigned*)(ws + MAP_B);
    float* invn     = (float*)(ws + 2 * MAP_B);          // [2][B][N]
    float* lse_base = (float*)(ws + 2 * MAP_B + 2 * PIX_B);
    float* pos_sim  = (float*)(ws + 2 * MAP_B + 3 * PIX_B);
    float* max_neg  = (float*)(ws + 2 * MAP_B + 4 * PIX_B);
    float* lse_hard = (float*)(ws + 2 * MAP_B + 5 * PIX_B);
    float* max_hard = (float*)(ws + 2 * MAP_B + 5 * PIX_B + 8192);
    float* acc      = (float*)(ws + 2 * MAP_B + 5 * PIX_B + 2 * 8192);

    hipMemsetAsync(acc, 0, 16, stream);
    k1_norm_T<<<2048, 256, 0, stream>>>(rgb, dep, rgbT, depT, invn);
    k2_main<<<B_ * (N_ / 64), 256, 0, stream>>>(depT, rgbT, invn, coords, rand_i,
                                                lse_base, pos_sim, max_neg);
    k3_hard<<<B_ * NPOS, 128, 0, stream>>>(depT, rgbT, invn, coords, hoffu, hoffv,
                                           lse_hard, max_hard);
    k4_reduce<<<(B_ * N_) / 256, 256, 0, stream>>>(lse_base, pos_sim, max_neg,
                                                   mask, lse_hard, max_hard, acc);
    k5_final<<<1, 64, 0, stream>>>(acc, out);
}